// Round 11
// baseline (132.693 us; speedup 1.0000x reference)
//
#include <hip/hip_runtime.h>
#include <math.h>

// out = gelu(rowmean(x@W^T - subtract) + logN) + x
// rowmean(x@W^T)[m] = (1/N) * dot(x[m,:], colsum(W)).  No GEMM needed.
//
// R11: block-per-row continuous pipeline.
//  - wsum fragment hoisted to 16 VGPRs (fixed thread<->column map): the
//    VMEM companion stream of R3/R10 is GONE (halves read-phase VMEM ops).
//  - 8 rows/block; next row's 4 loads issued before current row's
//    reduce+store -> read and write streams always simultaneously in flight.
//  - ONE barrier per row (parity-double-buffered LDS reduce slots).
//  - plain x loads (keeps cross-replay L3 carryover), NT stores.

typedef float f4 __attribute__((ext_vector_type(4)));

#define ROWS_PER_BLOCK 8

// Kernel A: wsum[k] = sum_n W[n,k] (atomics over row-chunks).
// Last grid.y slice (blockIdx.x==0) also computes submean = mean(subtract).
__global__ __launch_bounds__(256) void colsum_kernel(
    const float* __restrict__ w, const float* __restrict__ sub,
    float* __restrict__ wsum, float* __restrict__ submean,
    int N, int K, int rows_per_block, float invN) {
    if (blockIdx.y == gridDim.y - 1) {
        if (blockIdx.x != 0) return;
        float acc = 0.f;
        for (int i = threadIdx.x; i < N; i += 256) acc += sub[i];
        #pragma unroll
        for (int off = 32; off > 0; off >>= 1) acc += __shfl_down(acc, off, 64);
        __shared__ float sd[4];
        if ((threadIdx.x & 63) == 0) sd[threadIdx.x >> 6] = acc;
        __syncthreads();
        if (threadIdx.x == 0) submean[0] = (sd[0] + sd[1] + sd[2] + sd[3]) * invN;
        return;
    }
    const int K4 = K >> 2;
    const int col4 = blockIdx.x * blockDim.x + threadIdx.x;
    if (col4 >= K4) return;
    const int row0 = blockIdx.y * rows_per_block;
    int row1 = row0 + rows_per_block;
    if (row1 > N) row1 = N;
    const f4* w4 = (const f4*)w;
    f4 acc = (f4)(0.f);
    for (int n = row0; n < row1; ++n) {
        acc += __builtin_nontemporal_load(&w4[(size_t)n * K4 + col4]);
    }
    float* dst = wsum + (size_t)col4 * 4;
    atomicAdd(dst + 0, acc.x);
    atomicAdd(dst + 1, acc.y);
    atomicAdd(dst + 2, acc.z);
    atomicAdd(dst + 3, acc.w);
}

// Kernel B: 8 consecutive rows per 256-thread block, pipelined.
__global__ __launch_bounds__(256) void fused_rows_kernel(
    const float* __restrict__ x, const float* __restrict__ wsum,
    const float* __restrict__ submean_p, float* __restrict__ out,
    int K, float logN, float invN) {
    const int tid  = threadIdx.x;
    const int wave = tid >> 6;
    const int lane = tid & 63;
    const size_t row0 = (size_t)blockIdx.x * ROWS_PER_BLOCK;

    // Hoist this thread's wsum fragment into registers (loop-invariant).
    const f4* ws4 = (const f4*)wsum;
    f4 wsr[4];
    #pragma unroll
    for (int j = 0; j < 4; ++j) wsr[j] = ws4[j * 256 + tid];

    const float sm = submean_p[0];
    __shared__ float sd[2][4];

    // Prologue: load row 0.
    f4 xa[4], xb[4];
    {
        const f4* xr = (const f4*)(x + row0 * K);
        #pragma unroll
        for (int j = 0; j < 4; ++j) xa[j] = xr[j * 256 + tid];
    }

    #pragma unroll 1
    for (int t = 0; t < ROWS_PER_BLOCK; ++t) {
        // Issue next row's loads FIRST; they stay in flight through the
        // reduce and the current row's stores.
        if (t + 1 < ROWS_PER_BLOCK) {
            const f4* xn = (const f4*)(x + (row0 + t + 1) * K);
            #pragma unroll
            for (int j = 0; j < 4; ++j) xb[j] = xn[j * 256 + tid];
        }

        // Per-thread dot (16 FMAs against register-resident wsum).
        f4 a = xa[0] * wsr[0] + xa[1] * wsr[1] + xa[2] * wsr[2] + xa[3] * wsr[3];
        float dot = (a.x + a.y) + (a.z + a.w);

        #pragma unroll
        for (int off = 1; off < 64; off <<= 1) dot += __shfl_xor(dot, off, 64);

        const int p = t & 1;
        if (lane == 0) sd[p][wave] = dot;
        __syncthreads();                       // the ONLY barrier per row
        const float total = (sd[p][0] + sd[p][1]) + (sd[p][2] + sd[p][3]);

        // All threads compute g redundantly (saves a second barrier).
        const float c = total * invN - sm + logN;
        const float tt = 0.7978845608028654f * fmaf(0.044715f * c, c * c, c);
        const float g = 0.5f * c * (1.f + tt / (fabsf(tt) + 1.f));

        f4* o4 = (f4*)(out + (row0 + t) * K);
        #pragma unroll
        for (int j = 0; j < 4; ++j)
            __builtin_nontemporal_store(xa[j] + (f4)(g), &o4[j * 256 + tid]);

        #pragma unroll
        for (int j = 0; j < 4; ++j) xa[j] = xb[j];   // rotate (16 v_mov)
    }
}

extern "C" void kernel_launch(void* const* d_in, const int* in_sizes, int n_in,
                              void* d_out, int out_size, void* d_ws, size_t ws_size,
                              hipStream_t stream) {
    const float* x   = (const float*)d_in[0];
    const float* w   = (const float*)d_in[1];
    const float* sub = (const float*)d_in[2];
    float* out = (float*)d_out;

    const int N = in_sizes[2];            // 4096
    const int K = in_sizes[1] / N;        // 4096
    const int M = in_sizes[0] / K;        // 16384

    float* wsum    = (float*)d_ws;        // K floats
    float* submean = wsum + K;            // 1 float

    (void)hipMemsetAsync(d_ws, 0, (size_t)(K + 1) * sizeof(float), stream);

    const int K4 = K / 4;
    const int rows_per_block = 16;
    dim3 gA((K4 + 255) / 256, N / rows_per_block + 1);
    colsum_kernel<<<gA, 256, 0, stream>>>(w, sub, wsum, submean,
                                          N, K, rows_per_block, 1.0f / (float)N);

    fused_rows_kernel<<<M / ROWS_PER_BLOCK, 256, 0, stream>>>(
        x, wsum, submean, out, K, logf((float)N), 1.0f / (float)N);
}

// Round 12
// 132.661 us; speedup vs baseline: 1.0002x; 1.0002x over previous
//
#include <hip/hip_runtime.h>
#include <math.h>

// out = gelu(rowmean(x@W^T - subtract) + logN) + x
// rowmean(x@W^T)[m] = (1/N) * dot(x[m,:], colsum(W)).  No GEMM needed.
//
// R12: global_load_lds DMA pipeline.  x streams HBM->LDS directly (no VGPR
// round-trip); per-wave double-buffered 16KB row slots; counted vmcnt waits
// (never drain-to-0 in the loop); no barriers; NT stores.

typedef float f4 __attribute__((ext_vector_type(4)));

// Kernel A: wsum[k] = sum_n W[n,k] (atomics over row-chunks).
// Last grid.y slice (blockIdx.x==0) also computes submean = mean(subtract).
__global__ __launch_bounds__(256) void colsum_kernel(
    const float* __restrict__ w, const float* __restrict__ sub,
    float* __restrict__ wsum, float* __restrict__ submean,
    int N, int K, int rows_per_block, float invN) {
    if (blockIdx.y == gridDim.y - 1) {
        if (blockIdx.x != 0) return;
        float acc = 0.f;
        for (int i = threadIdx.x; i < N; i += 256) acc += sub[i];
        #pragma unroll
        for (int off = 32; off > 0; off >>= 1) acc += __shfl_down(acc, off, 64);
        __shared__ float sd[4];
        if ((threadIdx.x & 63) == 0) sd[threadIdx.x >> 6] = acc;
        __syncthreads();
        if (threadIdx.x == 0) submean[0] = (sd[0] + sd[1] + sd[2] + sd[3]) * invN;
        return;
    }
    const int K4 = K >> 2;
    const int col4 = blockIdx.x * blockDim.x + threadIdx.x;
    if (col4 >= K4) return;
    const int row0 = blockIdx.y * rows_per_block;
    int row1 = row0 + rows_per_block;
    if (row1 > N) row1 = N;
    const f4* w4 = (const f4*)w;
    f4 acc = (f4)(0.f);
    for (int n = row0; n < row1; ++n) {
        acc += __builtin_nontemporal_load(&w4[(size_t)n * K4 + col4]);
    }
    float* dst = wsum + (size_t)col4 * 4;
    atomicAdd(dst + 0, acc.x);
    atomicAdd(dst + 1, acc.y);
    atomicAdd(dst + 2, acc.z);
    atomicAdd(dst + 3, acc.w);
}

// Kernel B: 128 threads = 2 waves; each wave owns rows_per_wave consecutive
// rows with two private 16KB LDS buffers (64KB/block -> 2 blocks/CU).
// Steady state per row: issue 16 DMA calls for row t+1, counted
// s_waitcnt vmcnt(32) (row t's DMAs retired; t+1's DMAs + previous stores
// still in flight), ds_read+dot, shuffle-reduce, gelu, 16 NT stores.
__global__ __launch_bounds__(128) void fused_dma_kernel(
    const float* __restrict__ x, const float* __restrict__ wsum,
    const float* __restrict__ submean_p, float* __restrict__ out,
    int K, int rows_per_wave, float logN, float invN) {
    __shared__ float lds[16384];           // 2 waves x 2 bufs x 4096 floats
    const int lane = threadIdx.x & 63;
    const int w    = threadIdx.x >> 6;     // 0..1
    const size_t row0 = ((size_t)blockIdx.x * 2 + w) * rows_per_wave;

    // Hoist wsum fragment into registers (shared by all rows of this wave).
    const f4* ws4 = (const f4*)wsum;
    f4 wsr[16];
    #pragma unroll
    for (int j = 0; j < 16; ++j) wsr[j] = ws4[j * 64 + lane];
    const float sm = submean_p[0];
    // Drain scalar/frag loads so DMA vmcnt bookkeeping below starts at 0.
    asm volatile("s_waitcnt vmcnt(0)" ::: "memory");

    float* slot0 = &lds[(w * 2 + 0) * 4096];
    float* slot1 = &lds[(w * 2 + 1) * 4096];

    // Prologue: DMA row 0 into slot0 (16 calls x 1KB).
    {
        const float* xr = x + row0 * (size_t)K;
        #pragma unroll
        for (int c = 0; c < 16; ++c)
            __builtin_amdgcn_global_load_lds(
                (const __attribute__((address_space(1))) void*)(xr + c * 256 + lane * 4),
                (__attribute__((address_space(3))) void*)(slot0 + c * 256),
                16, 0, 0);
    }

    for (int i = 0; i < rows_per_wave; ++i) {
        float* cur = (i & 1) ? slot1 : slot0;
        float* nxt = (i & 1) ? slot0 : slot1;
        const bool has_next = (i + 1) < rows_per_wave;

        if (has_next) {
            const float* xr = x + (row0 + i + 1) * (size_t)K;
            #pragma unroll
            for (int c = 0; c < 16; ++c)
                __builtin_amdgcn_global_load_lds(
                    (const __attribute__((address_space(1))) void*)(xr + c * 256 + lane * 4),
                    (__attribute__((address_space(3))) void*)(nxt + c * 256),
                    16, 0, 0);
        }

        // Counted waits: guarantee cur's 16 DMAs (the oldest VMEM ops)
        // retired; keep next DMAs and prior NT stores in flight.
        if (i == 0 || !has_next) {
            asm volatile("s_waitcnt vmcnt(16)" ::: "memory");
        } else {
            asm volatile("s_waitcnt vmcnt(32)" ::: "memory");
        }

        // Consume cur from LDS: dot vs register wsum (xv held for store).
        f4 xv[16];
        f4 acc = (f4)(0.f);
        #pragma unroll
        for (int j = 0; j < 16; ++j) {
            xv[j] = *(const f4*)&cur[j * 256 + lane * 4];
            acc += xv[j] * wsr[j];
        }
        float dot = (acc.x + acc.y) + (acc.z + acc.w);

        #pragma unroll
        for (int off = 1; off < 64; off <<= 1) dot += __shfl_xor(dot, off, 64);

        const float c = dot * invN - sm + logN;
        const float tt = 0.7978845608028654f * fmaf(0.044715f * c, c * c, c);
        const float g = 0.5f * c * (1.f + tt / (fabsf(tt) + 1.f));

        f4* o4 = (f4*)(out + (row0 + i) * (size_t)K);
        #pragma unroll
        for (int j = 0; j < 16; ++j)
            __builtin_nontemporal_store(xv[j] + (f4)(g), &o4[j * 64 + lane]);
    }
}

extern "C" void kernel_launch(void* const* d_in, const int* in_sizes, int n_in,
                              void* d_out, int out_size, void* d_ws, size_t ws_size,
                              hipStream_t stream) {
    const float* x   = (const float*)d_in[0];
    const float* w   = (const float*)d_in[1];
    const float* sub = (const float*)d_in[2];
    float* out = (float*)d_out;

    const int N = in_sizes[2];            // 4096
    const int K = in_sizes[1] / N;        // 4096
    const int M = in_sizes[0] / K;        // 16384

    float* wsum    = (float*)d_ws;        // K floats
    float* submean = wsum + K;            // 1 float

    (void)hipMemsetAsync(d_ws, 0, (size_t)(K + 1) * sizeof(float), stream);

    const int K4 = K / 4;
    const int rows_per_block = 16;
    dim3 gA((K4 + 255) / 256, N / rows_per_block + 1);
    colsum_kernel<<<gA, 256, 0, stream>>>(w, sub, wsum, submean,
                                          N, K, rows_per_block, 1.0f / (float)N);

    // 512 blocks x 2 waves = 1024 waves; 16 rows each (M = 16384).
    const int nblocks = 512;
    const int rows_per_wave = M / (nblocks * 2);
    fused_dma_kernel<<<nblocks, 128, 0, stream>>>(
        x, wsum, submean, out, K, rows_per_wave, logf((float)N), 1.0f / (float)N);
}